// Round 7
// baseline (676.845 us; speedup 1.0000x reference)
//
#include <hip/hip_runtime.h>
#include <hip/hip_bf16.h>

#define DIM 128
#define K 8
#define EPS 1e-8f
#define SQRT_EPS 1e-6f

#define CB 512           // clauses per bucket
#define CSHIFT 9
#define NBMAX 4096       // max buckets (n_clauses/CB = 3907 here)
#define SBLK 1024        // partition blocks
#define MAXSLOT 32       // graph slots per bucket
#define PF 4             // edge-loop pipeline depth

typedef __attribute__((ext_vector_type(8))) short bf16x8;
typedef __attribute__((ext_vector_type(4))) float f32x4;

__device__ inline short bfc(float f) {
    union { __hip_bfloat16 h; short s; } u;
    u.h = __float2bfloat16(f);
    return u.s;
}

#define LDW 136  // padded LDS row (bf16 elements)

// ---------------- MLP via MFMA: logits = relu(x@W1+b1)@W2+b2 -> fp8 ----------
__global__ __launch_bounds__(256) void mlp_kernel(
    const float* __restrict__ x, const float* __restrict__ W1,
    const float* __restrict__ b1, const float* __restrict__ W2,
    const float* __restrict__ b2, uint2* __restrict__ lfp8, int n_vars)
{
    __shared__ __align__(16) short w1t[DIM][LDW];     // W1^T as bf16 (34.8 KB)
    __shared__ __align__(16) short w2t[16][LDW];      // W2^T (cols 8..15 zero)
    __shared__ __align__(16) short hlds[4][16][LDW];  // per-wave H row-tile
    __shared__ __align__(16) float lout[4][32][8];    // per-wave logit rows (4 KB)

    const int t = threadIdx.x;
    const int wave = t >> 6, lane = t & 63;
    const int lr = lane & 15, lg = lane >> 4;

    for (int i = t; i < DIM * DIM; i += 256) {
        int r = i >> 7, c = i & 127;
        w1t[c][r] = bfc(W1[i]);
    }
    for (int i = t; i < 16 * DIM; i += 256) {
        int c = i >> 7, j = i & 127;
        w2t[c][j] = (c < 8) ? bfc(W2[j * 8 + c]) : (short)0;
    }
    __syncthreads();

    const int rbase = blockIdx.x * 128 + wave * 32;

    bf16x8 a[2][4];
    #pragma unroll
    for (int rt = 0; rt < 2; ++rt) {
        int row = rbase + rt * 16 + lr;
        bool ok = row < n_vars;
        const float* xp = x + (size_t)row * DIM + lg * 8;
        #pragma unroll
        for (int kt = 0; kt < 4; ++kt) {
            bf16x8 av = {0,0,0,0,0,0,0,0};
            if (ok) {
                float4 f0 = *(const float4*)(xp + kt * 32);
                float4 f1 = *(const float4*)(xp + kt * 32 + 4);
                av[0]=bfc(f0.x); av[1]=bfc(f0.y); av[2]=bfc(f0.z); av[3]=bfc(f0.w);
                av[4]=bfc(f1.x); av[5]=bfc(f1.y); av[6]=bfc(f1.z); av[7]=bfc(f1.w);
            }
            a[rt][kt] = av;
        }
    }

    bf16x8 bb[4];
    #pragma unroll
    for (int kt = 0; kt < 4; ++kt)
        bb[kt] = *(const bf16x8*)&w2t[lr][kt * 32 + lg * 8];
    float b2v = (lr < 8) ? b2[lr] : 0.f;

    #pragma unroll
    for (int rt = 0; rt < 2; ++rt) {
        #pragma unroll
        for (int n = 0; n < 8; ++n) {
            f32x4 acc = {0.f, 0.f, 0.f, 0.f};
            #pragma unroll
            for (int kt = 0; kt < 4; ++kt) {
                bf16x8 bf = *(const bf16x8*)&w1t[n * 16 + lr][kt * 32 + lg * 8];
                acc = __builtin_amdgcn_mfma_f32_16x16x32_bf16(a[rt][kt], bf, acc, 0, 0, 0);
            }
            float bcol = b1[n * 16 + lr];
            #pragma unroll
            for (int r = 0; r < 4; ++r) {
                float h = fmaxf(acc[r] + bcol, 0.f);
                hlds[wave][lg * 4 + r][n * 16 + lr] = bfc(h);
            }
        }
        f32x4 acc2 = {0.f, 0.f, 0.f, 0.f};
        #pragma unroll
        for (int kt = 0; kt < 4; ++kt) {
            bf16x8 af = *(const bf16x8*)&hlds[wave][lr][kt * 32 + lg * 8];
            acc2 = __builtin_amdgcn_mfma_f32_16x16x32_bf16(af, bb[kt], acc2, 0, 0, 0);
        }
        if (lr < 8) {
            #pragma unroll
            for (int r = 0; r < 4; ++r)
                lout[wave][rt * 16 + lg * 4 + r][lr] = acc2[r] + b2v;
        }
    }

    // pack 8 f32 -> 8 fp8 (e4m3, hardware cvt) per row; lanes 0..31 of each wave
    __syncthreads();
    if (lane < 32) {
        int row = rbase + lane;
        if (row < n_vars) {
            const float* f = lout[wave][lane];
            unsigned lo = 0u, hi = 0u;
            lo = __builtin_amdgcn_cvt_pk_fp8_f32(f[0], f[1], lo, false);
            lo = __builtin_amdgcn_cvt_pk_fp8_f32(f[2], f[3], lo, true);
            hi = __builtin_amdgcn_cvt_pk_fp8_f32(f[4], f[5], hi, false);
            hi = __builtin_amdgcn_cvt_pk_fp8_f32(f[6], f[7], hi, true);
            lfp8[row] = make_uint2(lo, hi);
        }
    }
}

// ---------------- Pass 0: per-block bucket histogram (LDS only) --------------
__global__ __launch_bounds__(256) void count_kernel(
    const int* __restrict__ ci, unsigned* __restrict__ hist,
    int n_edges, int nb, int tile)
{
    __shared__ unsigned hl[NBMAX];
    const int t = threadIdx.x, b = blockIdx.x;
    for (int i = t; i < nb; i += 256) hl[i] = 0u;
    __syncthreads();
    const int e0 = b * tile, e1 = min(e0 + tile, n_edges);
    for (int e = e0 + t; e < e1; e += 256)
        atomicAdd(&hl[(unsigned)ci[e] >> CSHIFT], 1u);
    __syncthreads();
    for (int i = t; i < nb; i += 256) hist[(size_t)i * SBLK + b] = hl[i];
}

// ---------------- Pass 0b: exclusive scan of each bucket row over blocks -----
__global__ __launch_bounds__(256) void scan1_kernel(
    unsigned* __restrict__ hist, unsigned* __restrict__ btotal)
{
    const int t = threadIdx.x;
    const size_t base = (size_t)blockIdx.x * SBLK + t * 4;
    uint4 v = *(const uint4*)(hist + base);
    unsigned pre0 = 0, pre1 = v.x, pre2 = v.x + v.y, pre3 = v.x + v.y + v.z;
    unsigned run = pre3 + v.w;

    __shared__ unsigned ts[256];
    ts[t] = run;
    __syncthreads();
    for (int off = 1; off < 256; off <<= 1) {
        unsigned xv = (t >= off) ? ts[t - off] : 0u;
        __syncthreads();
        ts[t] += xv;
        __syncthreads();
    }
    unsigned ex = ts[t] - run;
    uint4 o = {ex + pre0, ex + pre1, ex + pre2, ex + pre3};
    *(uint4*)(hist + base) = o;
    if (t == 255) btotal[blockIdx.x] = ts[255];
}

// ---------------- Pass 0c: scan bucket totals -> bucket_base -----------------
__global__ __launch_bounds__(256) void scan2_kernel(
    const unsigned* __restrict__ btotal, unsigned* __restrict__ bbase, int nb)
{
    const int t = threadIdx.x;
    unsigned loc[16];
    unsigned run = 0;
    #pragma unroll
    for (int it = 0; it < 16; ++it) {
        int idx = t * 16 + it;
        unsigned v = (idx < nb) ? btotal[idx] : 0u;
        loc[it] = run;
        run += v;
    }
    __shared__ unsigned ts[256];
    ts[t] = run;
    __syncthreads();
    for (int off = 1; off < 256; off <<= 1) {
        unsigned xv = (t >= off) ? ts[t - off] : 0u;
        __syncthreads();
        ts[t] += xv;
        __syncthreads();
    }
    unsigned ex = ts[t] - run;
    #pragma unroll
    for (int it = 0; it < 16; ++it) {
        int idx = t * 16 + it;
        if (idx <= nb) bbase[idx] = ex + loc[it];
    }
}

// ---------------- Pass 1: scatter packed payloads into bucket regions --------
__global__ __launch_bounds__(256) void scatter_kernel(
    const int* __restrict__ ci, const int* __restrict__ vi,
    const float* __restrict__ pol, const unsigned* __restrict__ hist,
    const unsigned* __restrict__ bbase, unsigned* __restrict__ sorted,
    int n_edges, int nb, int tile)
{
    __shared__ unsigned offs[NBMAX];
    const int t = threadIdx.x, b = blockIdx.x;
    for (int i = t; i < nb; i += 256)
        offs[i] = bbase[i] + hist[(size_t)i * SBLK + b];
    __syncthreads();
    const int e0 = b * tile, e1 = min(e0 + tile, n_edges);
    for (int e = e0 + t; e < e1; e += 256) {
        unsigned c = (unsigned)ci[e];
        unsigned v = (unsigned)vi[e];
        unsigned neg = (pol[e] < 0.f) ? 1u : 0u;
        unsigned pos = atomicAdd(&offs[c >> CSHIFT], 1u);
        sorted[pos] = (c & (CB - 1)) | (v << CSHIFT) | (neg << 28);
    }
}

// ---------------- Pass 2: per-bucket clause reduce + graph fuse --------------
__global__ __launch_bounds__(256) void bucket_kernel(
    const unsigned* __restrict__ sorted, const uint2* __restrict__ logit8,
    const unsigned* __restrict__ bbase, const int* __restrict__ clause_batch,
    float* __restrict__ per_graph, unsigned* __restrict__ gmask,
    int n_clauses, int n_graphs)
{
    __shared__ float acc[K * CB];       // 16 KB, transposed [j][cl] -> bank = cl%32
    __shared__ unsigned cmask[CB];      //  2 KB
    __shared__ float sp[2][256];        //  2 KB softplus table [neg][fp8 byte]
    __shared__ float pg[MAXSLOT * K];
    __shared__ unsigned pmask[MAXSLOT];
    __shared__ int sh_ghi;

    const int t = threadIdx.x;
    const int bkt = blockIdx.x;
    const int c_base = bkt << CSHIFT;
    const int n_cl = min(CB, n_clauses - c_base);

    // softplus table: byte t decoded as fp8 e4m3; both literal polarities.
    // Identical math to the previous per-edge computation -> bit-identical sums.
    {
        float v = __builtin_amdgcn_cvt_f32_fp8((unsigned)t, 0);
        float l = __logf(1.f + __expf(-fabsf(v)));
        sp[0][t] = fmaxf(v, 0.f) + l;    // pol = +1
        sp[1][t] = fmaxf(-v, 0.f) + l;   // pol = -1
    }
    for (int i = t; i < K * CB; i += 256) acc[i] = 0.f;
    for (int i = t; i < CB; i += 256) cmask[i] = 0u;
    for (int i = t; i < MAXSLOT * K; i += 256) pg[i] = 0.f;
    if (t < MAXSLOT) pmask[t] = 0xFFu;
    if (t == 0) sh_ghi = clause_batch[c_base + n_cl - 1];
    __syncthreads();

    const unsigned lo = bbase[bkt], hi = bbase[bkt + 1];

    for (unsigned base = lo + t; base < hi; base += 256u * PF) {
        unsigned pay[PF];
        uint2 g[PF];
        #pragma unroll
        for (int u = 0; u < PF; ++u) {
            unsigned e = base + 256u * u;
            pay[u] = (e < hi) ? sorted[e] : 0xFFFFFFFFu;
        }
        #pragma unroll
        for (int u = 0; u < PF; ++u) {
            if (pay[u] != 0xFFFFFFFFu)
                g[u] = logit8[(pay[u] >> CSHIFT) & 0x7FFFF];
        }
        #pragma unroll
        for (int u = 0; u < PF; ++u) {
            if (pay[u] == 0xFFFFFFFFu) continue;
            unsigned cl = pay[u] & (CB - 1);
            unsigned neg = (pay[u] >> 28) & 1u;
            const float* spt = sp[neg];
            unsigned gt0 = 0u;
            #pragma unroll
            for (int j = 0; j < 4; ++j) {
                unsigned b0 = (g[u].x >> (8 * j)) & 0xFFu;
                unsigned b1 = (g[u].y >> (8 * j)) & 0xFFu;
                atomicAdd(&acc[j * CB + cl], spt[b0]);
                atomicAdd(&acc[(j + 4) * CB + cl], spt[b1]);
                gt0 |= (b0 - 1u < 0x7Fu) ? (1u << j) : 0u;       // b0 in [1,0x7F]
                gt0 |= (b1 - 1u < 0x7Fu) ? (1u << (j + 4)) : 0u;
            }
            unsigned em = gt0 ^ (neg ? 0xFFu : 0u);
            atomicOr(&cmask[cl], em | 0x100u);
        }
    }
    __syncthreads();

    // fold clauses into per-graph slots (register-local accumulation)
    const int g_lo = clause_batch[c_base];
    float lacc[K];
    unsigned land = 0xFFu;
    int cur = -1;
    for (int cl = t; cl < n_cl; cl += 256) {
        int c = c_base + cl;
        int gg = clause_batch[c];
        int slot = gg - g_lo;
        if (slot != cur) {
            if (cur >= 0) {
                if (cur < MAXSLOT) {
                    #pragma unroll
                    for (int j = 0; j < K; ++j) atomicAdd(&pg[cur * K + j], lacc[j]);
                    atomicAnd(&pmask[cur], land);
                } else {
                    #pragma unroll
                    for (int j = 0; j < K; ++j) atomicAdd(&per_graph[(size_t)(g_lo + cur) * K + j], lacc[j]);
                    atomicAnd(&gmask[g_lo + cur], land);
                }
            }
            cur = slot;
            #pragma unroll
            for (int j = 0; j < K; ++j) lacc[j] = 0.f;
            land = 0xFFu;
        }
        unsigned m = cmask[cl];
        unsigned em8 = (m & 0x100u) ? (m & 0xFFu) : 0u;
        land &= em8;
        #pragma unroll
        for (int j = 0; j < K; ++j) {
            float s = acc[j * CB + cl];
            float cv = __expf(-s);
            lacc[j] += cv * (-__logf(1.f - cv + EPS));
        }
    }
    if (cur >= 0) {
        if (cur < MAXSLOT) {
            #pragma unroll
            for (int j = 0; j < K; ++j) atomicAdd(&pg[cur * K + j], lacc[j]);
            atomicAnd(&pmask[cur], land);
        } else {
            #pragma unroll
            for (int j = 0; j < K; ++j) atomicAdd(&per_graph[(size_t)(g_lo + cur) * K + j], lacc[j]);
            atomicAnd(&gmask[g_lo + cur], land);
        }
    }
    __syncthreads();

    const int nslots = min(sh_ghi - g_lo + 1, MAXSLOT);
    if (t < nslots * K) {
        int s = t >> 3, j = t & 7;
        atomicAdd(&per_graph[(size_t)(g_lo + s) * K + j], pg[s * K + j]);
    }
    if (t < nslots) atomicAnd(&gmask[g_lo + t], pmask[t]);
}

// ---------------- Final: per-graph sqrt, sort-8, cost dot, solved ------------
__global__ __launch_bounds__(256) void final_kernel(
    const float* __restrict__ per_graph, const unsigned* __restrict__ gmask,
    int n_graphs, float* __restrict__ out)
{
    const int t = threadIdx.x;
    float dot = 0.f;
    if (t < n_graphs) {
        float v[K];
        #pragma unroll
        for (int j = 0; j < K; ++j)
            v[j] = sqrtf(per_graph[(size_t)t * K + j] + SQRT_EPS) - sqrtf(SQRT_EPS);
        #pragma unroll
        for (int i = 1; i < K; ++i) {
            float key = v[i];
            int j = i - 1;
            while (j >= 0 && v[j] < key) { v[j + 1] = v[j]; --j; }
            v[j + 1] = key;
        }
        #pragma unroll
        for (int i = 0; i < K; ++i)
            dot = fmaf(v[i], (float)((i + 1) * (i + 1)), dot);
        out[1 + t] = (gmask[t] & 0xFFu) ? 1.f : 0.f;
    }
    __shared__ float red[256];
    red[t] = dot;
    __syncthreads();
    for (int s = 128; s >= 1; s >>= 1) {
        if (t < s) red[t] += red[t + s];
        __syncthreads();
    }
    if (t == 0) out[0] = red[0] * (1.f / 204.f);
}

// ---------------------------------------------------------------------------
extern "C" void kernel_launch(void* const* d_in, const int* in_sizes, int n_in,
                              void* d_out, int out_size, void* d_ws, size_t ws_size,
                              hipStream_t stream) {
    const float* x   = (const float*)d_in[0];
    const float* pol = (const float*)d_in[1];
    const int* vi    = (const int*)d_in[2];
    const int* ci    = (const int*)d_in[3];
    const int* cb    = (const int*)d_in[4];
    const float* W1  = (const float*)d_in[5];
    const float* b1  = (const float*)d_in[6];
    const float* W2  = (const float*)d_in[7];
    const float* b2  = (const float*)d_in[8];

    const int n_vars    = in_sizes[0] / DIM;
    const int n_edges   = in_sizes[1];
    const int n_clauses = in_sizes[4];
    const int n_graphs  = out_size - 1;
    const int nb        = (n_clauses + CB - 1) / CB;
    const int tile      = (n_edges + SBLK - 1) / SBLK;

    // ---- workspace layout (256B aligned regions) ----
    char* ws = (char*)d_ws;
    size_t off = 0;
    auto alloc = [&](size_t bytes) { char* p = ws + off; off += (bytes + 255) & ~(size_t)255; return p; };
    uint2*    lfp8     = (uint2*)alloc((size_t)n_vars * 8);                // 4 MB fp8
    unsigned* sorted   = (unsigned*)alloc((size_t)n_edges * 4);            // 24 MB
    unsigned* hist     = (unsigned*)alloc((size_t)NBMAX * SBLK * 4);       // 16 MB
    unsigned* btotal   = (unsigned*)alloc((size_t)NBMAX * 4);
    unsigned* bbase    = (unsigned*)alloc((size_t)(NBMAX + 1) * 4);
    float*    per_graph= (float*)alloc((size_t)n_graphs * K * 4);
    unsigned* gmask    = (unsigned*)alloc((size_t)n_graphs * 4);

    hipMemsetAsync(per_graph, 0, (size_t)n_graphs * K * 4, stream);
    hipMemsetAsync(gmask, 0xFF, (size_t)n_graphs * 4, stream);

    count_kernel<<<SBLK, 256, 0, stream>>>(ci, hist, n_edges, nb, tile);
    scan1_kernel<<<nb, 256, 0, stream>>>(hist, btotal);
    scan2_kernel<<<1, 256, 0, stream>>>(btotal, bbase, nb);
    scatter_kernel<<<SBLK, 256, 0, stream>>>(ci, vi, pol, hist, bbase, sorted,
                                             n_edges, nb, tile);
    mlp_kernel<<<(n_vars + 127) / 128, 256, 0, stream>>>(x, W1, b1, W2, b2, lfp8, n_vars);
    bucket_kernel<<<nb, 256, 0, stream>>>(sorted, lfp8, bbase, cb,
                                          per_graph, gmask, n_clauses, n_graphs);
    final_kernel<<<1, 256, 0, stream>>>(per_graph, gmask, n_graphs, (float*)d_out);
}

// Round 8
// 658.591 us; speedup vs baseline: 1.0277x; 1.0277x over previous
//
#include <hip/hip_runtime.h>
#include <hip/hip_bf16.h>

#define DIM 128
#define K 8
#define EPS 1e-8f
#define SQRT_EPS 1e-6f

#define CB 512           // clauses per bucket
#define CSHIFT 9
#define NBMAX 4096       // max buckets (n_clauses/CB = 3907 here)
#define SBLK 1024        // partition blocks
#define SARR_CAP 2560    // in-LDS sorted-edge capacity (mean 1536, 26 sigma)

typedef __attribute__((ext_vector_type(8))) short bf16x8;
typedef __attribute__((ext_vector_type(4))) float f32x4;

__device__ inline short bfc(float f) {
    union { __hip_bfloat16 h; short s; } u;
    u.h = __float2bfloat16(f);
    return u.s;
}

#define LDW 136  // padded LDS row (bf16 elements)

// ---------------- MLP via MFMA: logits = relu(x@W1+b1)@W2+b2 -> fp8 ----------
__global__ __launch_bounds__(256) void mlp_kernel(
    const float* __restrict__ x, const float* __restrict__ W1,
    const float* __restrict__ b1, const float* __restrict__ W2,
    const float* __restrict__ b2, uint2* __restrict__ lfp8, int n_vars)
{
    __shared__ __align__(16) short w1t[DIM][LDW];     // W1^T as bf16 (34.8 KB)
    __shared__ __align__(16) short w2t[16][LDW];      // W2^T (cols 8..15 zero)
    __shared__ __align__(16) short hlds[4][16][LDW];  // per-wave H row-tile
    __shared__ __align__(16) float lout[4][32][8];    // per-wave logit rows (4 KB)

    const int t = threadIdx.x;
    const int wave = t >> 6, lane = t & 63;
    const int lr = lane & 15, lg = lane >> 4;

    for (int i = t; i < DIM * DIM; i += 256) {
        int r = i >> 7, c = i & 127;
        w1t[c][r] = bfc(W1[i]);
    }
    for (int i = t; i < 16 * DIM; i += 256) {
        int c = i >> 7, j = i & 127;
        w2t[c][j] = (c < 8) ? bfc(W2[j * 8 + c]) : (short)0;
    }
    __syncthreads();

    const int rbase = blockIdx.x * 128 + wave * 32;

    bf16x8 a[2][4];
    #pragma unroll
    for (int rt = 0; rt < 2; ++rt) {
        int row = rbase + rt * 16 + lr;
        bool ok = row < n_vars;
        const float* xp = x + (size_t)row * DIM + lg * 8;
        #pragma unroll
        for (int kt = 0; kt < 4; ++kt) {
            bf16x8 av = {0,0,0,0,0,0,0,0};
            if (ok) {
                float4 f0 = *(const float4*)(xp + kt * 32);
                float4 f1 = *(const float4*)(xp + kt * 32 + 4);
                av[0]=bfc(f0.x); av[1]=bfc(f0.y); av[2]=bfc(f0.z); av[3]=bfc(f0.w);
                av[4]=bfc(f1.x); av[5]=bfc(f1.y); av[6]=bfc(f1.z); av[7]=bfc(f1.w);
            }
            a[rt][kt] = av;
        }
    }

    bf16x8 bb[4];
    #pragma unroll
    for (int kt = 0; kt < 4; ++kt)
        bb[kt] = *(const bf16x8*)&w2t[lr][kt * 32 + lg * 8];
    float b2v = (lr < 8) ? b2[lr] : 0.f;

    #pragma unroll
    for (int rt = 0; rt < 2; ++rt) {
        #pragma unroll
        for (int n = 0; n < 8; ++n) {
            f32x4 acc = {0.f, 0.f, 0.f, 0.f};
            #pragma unroll
            for (int kt = 0; kt < 4; ++kt) {
                bf16x8 bf = *(const bf16x8*)&w1t[n * 16 + lr][kt * 32 + lg * 8];
                acc = __builtin_amdgcn_mfma_f32_16x16x32_bf16(a[rt][kt], bf, acc, 0, 0, 0);
            }
            float bcol = b1[n * 16 + lr];
            #pragma unroll
            for (int r = 0; r < 4; ++r) {
                float h = fmaxf(acc[r] + bcol, 0.f);
                hlds[wave][lg * 4 + r][n * 16 + lr] = bfc(h);
            }
        }
        f32x4 acc2 = {0.f, 0.f, 0.f, 0.f};
        #pragma unroll
        for (int kt = 0; kt < 4; ++kt) {
            bf16x8 af = *(const bf16x8*)&hlds[wave][lr][kt * 32 + lg * 8];
            acc2 = __builtin_amdgcn_mfma_f32_16x16x32_bf16(af, bb[kt], acc2, 0, 0, 0);
        }
        if (lr < 8) {
            #pragma unroll
            for (int r = 0; r < 4; ++r)
                lout[wave][rt * 16 + lg * 4 + r][lr] = acc2[r] + b2v;
        }
    }

    // pack 8 f32 -> 8 fp8 (e4m3, hardware cvt) per row; lanes 0..31 of each wave
    __syncthreads();
    if (lane < 32) {
        int row = rbase + lane;
        if (row < n_vars) {
            const float* f = lout[wave][lane];
            unsigned lo = 0u, hi = 0u;
            lo = __builtin_amdgcn_cvt_pk_fp8_f32(f[0], f[1], lo, false);
            lo = __builtin_amdgcn_cvt_pk_fp8_f32(f[2], f[3], lo, true);
            hi = __builtin_amdgcn_cvt_pk_fp8_f32(f[4], f[5], hi, false);
            hi = __builtin_amdgcn_cvt_pk_fp8_f32(f[6], f[7], hi, true);
            lfp8[row] = make_uint2(lo, hi);
        }
    }
}

// ---------------- Pass 0: per-block bucket histogram (LDS only) --------------
__global__ __launch_bounds__(256) void count_kernel(
    const int* __restrict__ ci, unsigned* __restrict__ hist,
    int n_edges, int nb, int tile)
{
    __shared__ unsigned hl[NBMAX];
    const int t = threadIdx.x, b = blockIdx.x;
    for (int i = t; i < nb; i += 256) hl[i] = 0u;
    __syncthreads();
    const int e0 = b * tile, e1 = min(e0 + tile, n_edges);
    for (int e = e0 + t; e < e1; e += 256)
        atomicAdd(&hl[(unsigned)ci[e] >> CSHIFT], 1u);
    __syncthreads();
    for (int i = t; i < nb; i += 256) hist[(size_t)i * SBLK + b] = hl[i];
}

// ---------------- Pass 0b: exclusive scan of each bucket row over blocks -----
__global__ __launch_bounds__(256) void scan1_kernel(
    unsigned* __restrict__ hist, unsigned* __restrict__ btotal)
{
    const int t = threadIdx.x;
    const size_t base = (size_t)blockIdx.x * SBLK + t * 4;
    uint4 v = *(const uint4*)(hist + base);
    unsigned pre0 = 0, pre1 = v.x, pre2 = v.x + v.y, pre3 = v.x + v.y + v.z;
    unsigned run = pre3 + v.w;

    __shared__ unsigned ts[256];
    ts[t] = run;
    __syncthreads();
    for (int off = 1; off < 256; off <<= 1) {
        unsigned xv = (t >= off) ? ts[t - off] : 0u;
        __syncthreads();
        ts[t] += xv;
        __syncthreads();
    }
    unsigned ex = ts[t] - run;
    uint4 o = {ex + pre0, ex + pre1, ex + pre2, ex + pre3};
    *(uint4*)(hist + base) = o;
    if (t == 255) btotal[blockIdx.x] = ts[255];
}

// ---------------- Pass 0c: scan bucket totals -> bucket_base -----------------
__global__ __launch_bounds__(256) void scan2_kernel(
    const unsigned* __restrict__ btotal, unsigned* __restrict__ bbase, int nb)
{
    const int t = threadIdx.x;
    unsigned loc[16];
    unsigned run = 0;
    #pragma unroll
    for (int it = 0; it < 16; ++it) {
        int idx = t * 16 + it;
        unsigned v = (idx < nb) ? btotal[idx] : 0u;
        loc[it] = run;
        run += v;
    }
    __shared__ unsigned ts[256];
    ts[t] = run;
    __syncthreads();
    for (int off = 1; off < 256; off <<= 1) {
        unsigned xv = (t >= off) ? ts[t - off] : 0u;
        __syncthreads();
        ts[t] += xv;
        __syncthreads();
    }
    unsigned ex = ts[t] - run;
    #pragma unroll
    for (int it = 0; it < 16; ++it) {
        int idx = t * 16 + it;
        if (idx <= nb) bbase[idx] = ex + loc[it];
    }
}

// ---------------- Pass 1: scatter packed payloads into bucket regions --------
__global__ __launch_bounds__(256) void scatter_kernel(
    const int* __restrict__ ci, const int* __restrict__ vi,
    const float* __restrict__ pol, const unsigned* __restrict__ hist,
    const unsigned* __restrict__ bbase, unsigned* __restrict__ sorted,
    int n_edges, int nb, int tile)
{
    __shared__ unsigned offs[NBMAX];
    const int t = threadIdx.x, b = blockIdx.x;
    for (int i = t; i < nb; i += 256)
        offs[i] = bbase[i] + hist[(size_t)i * SBLK + b];
    __syncthreads();
    const int e0 = b * tile, e1 = min(e0 + tile, n_edges);
    for (int e = e0 + t; e < e1; e += 256) {
        unsigned c = (unsigned)ci[e];
        unsigned v = (unsigned)vi[e];
        unsigned neg = (pol[e] < 0.f) ? 1u : 0u;
        unsigned pos = atomicAdd(&offs[c >> CSHIFT], 1u);
        sorted[pos] = (c & (CB - 1)) | (v << CSHIFT) | (neg << 28);
    }
}

// ---------------- Pass 2: per-bucket clause-sort + register reduce -----------
__global__ __launch_bounds__(256) void bucket_kernel(
    const unsigned* __restrict__ sorted, const uint2* __restrict__ logit8,
    const unsigned* __restrict__ bbase, const int* __restrict__ clause_batch,
    float* __restrict__ per_graph, unsigned* __restrict__ gmask,
    int n_clauses, int n_graphs)
{
    __shared__ unsigned sarr[SARR_CAP];   // 10 KB clause-sorted payloads
    __shared__ unsigned cnt[CB];          //  2 KB
    __shared__ unsigned cofs[CB];         //  2 KB
    __shared__ unsigned cst[CB + 1];      //  2 KB
    __shared__ unsigned gslot[CB];        //  2 KB
    __shared__ unsigned cmsk[CB];         //  2 KB (em8 per clause)
    __shared__ float pcl[K][CB];          // 16 KB per-clause loss [j][cl]
    __shared__ float sp2[2][256];         //  2 KB softplus table
    __shared__ unsigned ts[256];
    __shared__ int sh_ghi;

    const int t = threadIdx.x;
    const int bkt = blockIdx.x;
    const int c_base = bkt << CSHIFT;
    const int n_cl = min(CB, n_clauses - c_base);
    const int g_lo = clause_batch[c_base];

    // softplus table (identical math to per-edge computation)
    {
        float v = __builtin_amdgcn_cvt_f32_fp8((unsigned)t, 0);
        float l = __logf(1.f + __expf(-fabsf(v)));
        sp2[0][t] = fmaxf(v, 0.f) + l;    // pol = +1
        sp2[1][t] = fmaxf(-v, 0.f) + l;   // pol = -1
    }
    for (int i = t; i < CB; i += 256) {
        cnt[i] = 0u;
        gslot[i] = (i < n_cl) ? (unsigned)(clause_batch[c_base + i] - g_lo) : 0xFFFFFFFFu;
    }
    if (t == 0) sh_ghi = clause_batch[c_base + n_cl - 1];
    __syncthreads();

    const unsigned lo = bbase[bkt], hi = bbase[bkt + 1];
    const int ne = (int)(hi - lo);

    if (ne <= SARR_CAP) {
        // ---- fast path: counting sort by clause, register accumulate ----
        for (unsigned e = lo + t; e < hi; e += 256)
            atomicAdd(&cnt[sorted[e] & (CB - 1)], 1u);
        __syncthreads();

        // exclusive scan of cnt[512] (2 elems/thread)
        unsigned a0 = cnt[2 * t], a1 = cnt[2 * t + 1];
        unsigned run = a0 + a1;
        ts[t] = run;
        __syncthreads();
        for (int off = 1; off < 256; off <<= 1) {
            unsigned xv = (t >= off) ? ts[t - off] : 0u;
            __syncthreads();
            ts[t] += xv;
            __syncthreads();
        }
        unsigned ex = ts[t] - run;
        cst[2 * t] = ex; cst[2 * t + 1] = ex + a0;
        cofs[2 * t] = ex; cofs[2 * t + 1] = ex + a0;
        if (t == 255) cst[CB] = ex + run;
        __syncthreads();

        // rank-scatter into clause-sorted LDS order (2nd sorted[] read: L2-hit)
        for (unsigned e = lo + t; e < hi; e += 256) {
            unsigned pay = sorted[e];
            unsigned r = atomicAdd(&cofs[pay & (CB - 1)], 1u);
            sarr[r] = pay;
        }
        __syncthreads();

        // each thread owns clauses 2t, 2t+1: accumulate in registers
        #pragma unroll
        for (int oc = 0; oc < 2; ++oc) {
            int cl = 2 * t + oc;
            if (cl >= n_cl) continue;
            unsigned s0 = cst[cl];
            int n = (int)(cst[cl + 1] - s0);
            float sums[K] = {0.f, 0.f, 0.f, 0.f, 0.f, 0.f, 0.f, 0.f};
            unsigned ormask = 0u;
            for (int base = 0; base < n; base += 8) {
                int m = min(8, n - base);
                unsigned pays[8]; uint2 gs[8];
                for (int i = 0; i < m; ++i) pays[i] = sarr[s0 + base + i];
                for (int i = 0; i < m; ++i) gs[i] = logit8[(pays[i] >> CSHIFT) & 0x7FFFF];
                for (int i = 0; i < m; ++i) {
                    unsigned neg = (pays[i] >> 28) & 1u;
                    const float* spt = sp2[neg];
                    unsigned gt0 = 0u;
                    #pragma unroll
                    for (int j = 0; j < 4; ++j) {
                        unsigned b0 = (gs[i].x >> (8 * j)) & 0xFFu;
                        unsigned b1 = (gs[i].y >> (8 * j)) & 0xFFu;
                        sums[j]     += spt[b0];
                        sums[j + 4] += spt[b1];
                        gt0 |= (b0 - 1u < 0x7Fu) ? (1u << j) : 0u;
                        gt0 |= (b1 - 1u < 0x7Fu) ? (1u << (j + 4)) : 0u;
                    }
                    ormask |= gt0 ^ (neg ? 0xFFu : 0u);
                }
            }
            #pragma unroll
            for (int j = 0; j < K; ++j) {
                float cv = __expf(-sums[j]);
                pcl[j][cl] = cv * (-__logf(1.f - cv + EPS));
            }
            cmsk[cl] = ormask;   // empty clause -> 0
        }
    } else {
        // ---- slow fallback (ne > SARR_CAP; statistically never) ----
        for (int i = t; i < K * CB; i += 256) ((float*)pcl)[i] = 0.f;
        for (int i = t; i < CB; i += 256) cmsk[i] = 0u;
        __syncthreads();
        for (unsigned e = lo + t; e < hi; e += 256) {
            unsigned pay = sorted[e];
            uint2 g = logit8[(pay >> CSHIFT) & 0x7FFFF];
            unsigned cl = pay & (CB - 1);
            unsigned neg = (pay >> 28) & 1u;
            const float* spt = sp2[neg];
            unsigned gt0 = 0u;
            #pragma unroll
            for (int j = 0; j < 4; ++j) {
                unsigned b0 = (g.x >> (8 * j)) & 0xFFu;
                unsigned b1 = (g.y >> (8 * j)) & 0xFFu;
                atomicAdd(&pcl[j][cl], spt[b0]);
                atomicAdd(&pcl[j + 4][cl], spt[b1]);
                gt0 |= (b0 - 1u < 0x7Fu) ? (1u << j) : 0u;
                gt0 |= (b1 - 1u < 0x7Fu) ? (1u << (j + 4)) : 0u;
            }
            atomicOr(&cmsk[cl], (gt0 ^ (neg ? 0xFFu : 0u)) | 0x100u);
        }
        __syncthreads();
        for (int oc = 0; oc < 2; ++oc) {
            int cl = 2 * t + oc;
            if (cl >= n_cl) continue;
            #pragma unroll
            for (int j = 0; j < K; ++j) {
                float cv = __expf(-pcl[j][cl]);
                pcl[j][cl] = cv * (-__logf(1.f - cv + EPS));
            }
            unsigned cm = cmsk[cl];
            cmsk[cl] = (cm & 0x100u) ? (cm & 0xFFu) : 0u;
        }
    }
    __syncthreads();

    // ---- clause -> graph fold: per-(slot,j) segment scan, 1 global atomic ---
    const int nslots = sh_ghi - g_lo + 1;
    for (int s = (t >> 3); s < nslots; s += 32) {
        int j = t & 7;
        float a = 0.f;
        for (int cl = 0; cl < n_cl; ++cl)
            if (gslot[cl] == (unsigned)s) a += pcl[j][cl];
        atomicAdd(&per_graph[(size_t)(g_lo + s) * K + j], a);
    }
    for (int s = t; s < nslots; s += 256) {
        unsigned m = 0xFFu;
        for (int cl = 0; cl < n_cl; ++cl)
            if (gslot[cl] == (unsigned)s) m &= cmsk[cl];
        atomicAnd(&gmask[g_lo + s], m);
    }
}

// ---------------- Final: per-graph sqrt, sort-8, cost dot, solved ------------
__global__ __launch_bounds__(256) void final_kernel(
    const float* __restrict__ per_graph, const unsigned* __restrict__ gmask,
    int n_graphs, float* __restrict__ out)
{
    const int t = threadIdx.x;
    float dot = 0.f;
    if (t < n_graphs) {
        float v[K];
        #pragma unroll
        for (int j = 0; j < K; ++j)
            v[j] = sqrtf(per_graph[(size_t)t * K + j] + SQRT_EPS) - sqrtf(SQRT_EPS);
        #pragma unroll
        for (int i = 1; i < K; ++i) {
            float key = v[i];
            int j = i - 1;
            while (j >= 0 && v[j] < key) { v[j + 1] = v[j]; --j; }
            v[j + 1] = key;
        }
        #pragma unroll
        for (int i = 0; i < K; ++i)
            dot = fmaf(v[i], (float)((i + 1) * (i + 1)), dot);
        out[1 + t] = (gmask[t] & 0xFFu) ? 1.f : 0.f;
    }
    __shared__ float red[256];
    red[t] = dot;
    __syncthreads();
    for (int s = 128; s >= 1; s >>= 1) {
        if (t < s) red[t] += red[t + s];
        __syncthreads();
    }
    if (t == 0) out[0] = red[0] * (1.f / 204.f);
}

// ---------------------------------------------------------------------------
extern "C" void kernel_launch(void* const* d_in, const int* in_sizes, int n_in,
                              void* d_out, int out_size, void* d_ws, size_t ws_size,
                              hipStream_t stream) {
    const float* x   = (const float*)d_in[0];
    const float* pol = (const float*)d_in[1];
    const int* vi    = (const int*)d_in[2];
    const int* ci    = (const int*)d_in[3];
    const int* cb    = (const int*)d_in[4];
    const float* W1  = (const float*)d_in[5];
    const float* b1  = (const float*)d_in[6];
    const float* W2  = (const float*)d_in[7];
    const float* b2  = (const float*)d_in[8];

    const int n_vars    = in_sizes[0] / DIM;
    const int n_edges   = in_sizes[1];
    const int n_clauses = in_sizes[4];
    const int n_graphs  = out_size - 1;
    const int nb        = (n_clauses + CB - 1) / CB;
    const int tile      = (n_edges + SBLK - 1) / SBLK;

    // ---- workspace layout (256B aligned regions) ----
    char* ws = (char*)d_ws;
    size_t off = 0;
    auto alloc = [&](size_t bytes) { char* p = ws + off; off += (bytes + 255) & ~(size_t)255; return p; };
    uint2*    lfp8     = (uint2*)alloc((size_t)n_vars * 8);                // 4 MB fp8
    unsigned* sorted   = (unsigned*)alloc((size_t)n_edges * 4);            // 24 MB
    unsigned* hist     = (unsigned*)alloc((size_t)NBMAX * SBLK * 4);       // 16 MB
    unsigned* btotal   = (unsigned*)alloc((size_t)NBMAX * 4);
    unsigned* bbase    = (unsigned*)alloc((size_t)(NBMAX + 1) * 4);
    float*    per_graph= (float*)alloc((size_t)n_graphs * K * 4);
    unsigned* gmask    = (unsigned*)alloc((size_t)n_graphs * 4);

    hipMemsetAsync(per_graph, 0, (size_t)n_graphs * K * 4, stream);
    hipMemsetAsync(gmask, 0xFF, (size_t)n_graphs * 4, stream);

    count_kernel<<<SBLK, 256, 0, stream>>>(ci, hist, n_edges, nb, tile);
    scan1_kernel<<<nb, 256, 0, stream>>>(hist, btotal);
    scan2_kernel<<<1, 256, 0, stream>>>(btotal, bbase, nb);
    scatter_kernel<<<SBLK, 256, 0, stream>>>(ci, vi, pol, hist, bbase, sorted,
                                             n_edges, nb, tile);
    mlp_kernel<<<(n_vars + 127) / 128, 256, 0, stream>>>(x, W1, b1, W2, b2, lfp8, n_vars);
    bucket_kernel<<<nb, 256, 0, stream>>>(sorted, lfp8, bbase, cb,
                                          per_graph, gmask, n_clauses, n_graphs);
    final_kernel<<<1, 256, 0, stream>>>(per_graph, gmask, n_graphs, (float*)d_out);
}

// Round 9
// 574.695 us; speedup vs baseline: 1.1777x; 1.1460x over previous
//
#include <hip/hip_runtime.h>
#include <hip/hip_bf16.h>

#define DIM 128
#define K 8
#define EPS 1e-8f
#define SQRT_EPS 1e-6f

#define CB 512           // clauses per bucket
#define CSHIFT 9
#define NBMAX 4096       // max cbuckets (3907 here)
#define SARR_CAP 2560    // in-LDS sorted-edge capacity (mean 1536, 26 sigma)

// radix partition params
#define T1 8192          // edges per pass-1 tile
#define NT1MAX 1024      // max pass-1 tiles
#define NK1 64           // coarse groups (cbkt >> 6)
#define T2 8192          // edges per pass-2 tile
#define MAXT2 48         // max tiles per coarse segment (48*8192=393K >> 26-sigma seg size)

typedef __attribute__((ext_vector_type(8))) short bf16x8;
typedef __attribute__((ext_vector_type(4))) float f32x4;

__device__ inline short bfc(float f) {
    union { __hip_bfloat16 h; short s; } u;
    u.h = __float2bfloat16(f);
    return u.s;
}

#define LDW 136  // padded LDS row (bf16 elements)

// ---------------- MLP via MFMA: logits = relu(x@W1+b1)@W2+b2 -> fp8 ----------
__global__ __launch_bounds__(256) void mlp_kernel(
    const float* __restrict__ x, const float* __restrict__ W1,
    const float* __restrict__ b1, const float* __restrict__ W2,
    const float* __restrict__ b2, uint2* __restrict__ lfp8, int n_vars)
{
    __shared__ __align__(16) short w1t[DIM][LDW];
    __shared__ __align__(16) short w2t[16][LDW];
    __shared__ __align__(16) short hlds[4][16][LDW];
    __shared__ __align__(16) float lout[4][32][8];

    const int t = threadIdx.x;
    const int wave = t >> 6, lane = t & 63;
    const int lr = lane & 15, lg = lane >> 4;

    for (int i = t; i < DIM * DIM; i += 256) {
        int r = i >> 7, c = i & 127;
        w1t[c][r] = bfc(W1[i]);
    }
    for (int i = t; i < 16 * DIM; i += 256) {
        int c = i >> 7, j = i & 127;
        w2t[c][j] = (c < 8) ? bfc(W2[j * 8 + c]) : (short)0;
    }
    __syncthreads();

    const int rbase = blockIdx.x * 128 + wave * 32;

    bf16x8 a[2][4];
    #pragma unroll
    for (int rt = 0; rt < 2; ++rt) {
        int row = rbase + rt * 16 + lr;
        bool ok = row < n_vars;
        const float* xp = x + (size_t)row * DIM + lg * 8;
        #pragma unroll
        for (int kt = 0; kt < 4; ++kt) {
            bf16x8 av = {0,0,0,0,0,0,0,0};
            if (ok) {
                float4 f0 = *(const float4*)(xp + kt * 32);
                float4 f1 = *(const float4*)(xp + kt * 32 + 4);
                av[0]=bfc(f0.x); av[1]=bfc(f0.y); av[2]=bfc(f0.z); av[3]=bfc(f0.w);
                av[4]=bfc(f1.x); av[5]=bfc(f1.y); av[6]=bfc(f1.z); av[7]=bfc(f1.w);
            }
            a[rt][kt] = av;
        }
    }

    bf16x8 bb[4];
    #pragma unroll
    for (int kt = 0; kt < 4; ++kt)
        bb[kt] = *(const bf16x8*)&w2t[lr][kt * 32 + lg * 8];
    float b2v = (lr < 8) ? b2[lr] : 0.f;

    #pragma unroll
    for (int rt = 0; rt < 2; ++rt) {
        #pragma unroll
        for (int n = 0; n < 8; ++n) {
            f32x4 acc = {0.f, 0.f, 0.f, 0.f};
            #pragma unroll
            for (int kt = 0; kt < 4; ++kt) {
                bf16x8 bf = *(const bf16x8*)&w1t[n * 16 + lr][kt * 32 + lg * 8];
                acc = __builtin_amdgcn_mfma_f32_16x16x32_bf16(a[rt][kt], bf, acc, 0, 0, 0);
            }
            float bcol = b1[n * 16 + lr];
            #pragma unroll
            for (int r = 0; r < 4; ++r) {
                float h = fmaxf(acc[r] + bcol, 0.f);
                hlds[wave][lg * 4 + r][n * 16 + lr] = bfc(h);
            }
        }
        f32x4 acc2 = {0.f, 0.f, 0.f, 0.f};
        #pragma unroll
        for (int kt = 0; kt < 4; ++kt) {
            bf16x8 af = *(const bf16x8*)&hlds[wave][lr][kt * 32 + lg * 8];
            acc2 = __builtin_amdgcn_mfma_f32_16x16x32_bf16(af, bb[kt], acc2, 0, 0, 0);
        }
        if (lr < 8) {
            #pragma unroll
            for (int r = 0; r < 4; ++r)
                lout[wave][rt * 16 + lg * 4 + r][lr] = acc2[r] + b2v;
        }
    }

    __syncthreads();
    if (lane < 32) {
        int row = rbase + lane;
        if (row < n_vars) {
            const float* f = lout[wave][lane];
            unsigned lo = 0u, hi = 0u;
            lo = __builtin_amdgcn_cvt_pk_fp8_f32(f[0], f[1], lo, false);
            lo = __builtin_amdgcn_cvt_pk_fp8_f32(f[2], f[3], lo, true);
            hi = __builtin_amdgcn_cvt_pk_fp8_f32(f[4], f[5], hi, false);
            hi = __builtin_amdgcn_cvt_pk_fp8_f32(f[6], f[7], hi, true);
            lfp8[row] = make_uint2(lo, hi);
        }
    }
}

// ================= two-level staged radix partition (coalesced writes) =======

// ---- P1 hist: per-tile histogram over 64 coarse groups (cbkt>>6 == ci>>15) --
__global__ __launch_bounds__(256) void hist1_kernel(
    const int* __restrict__ ci, unsigned* __restrict__ hist1, int n_edges)
{
    __shared__ unsigned h[NK1];
    const int t = threadIdx.x, b = blockIdx.x;
    if (t < NK1) h[t] = 0u;
    __syncthreads();
    const int e0 = b * T1, e1 = min(e0 + T1, n_edges);
    for (int e = e0 + t; e < e1; e += 256)
        atomicAdd(&h[((unsigned)ci[e]) >> 15], 1u);
    __syncthreads();
    if (t < NK1) hist1[(size_t)t * NT1MAX + b] = h[t];
}

// ---- P1 scan: exclusive scan of each coarse row over tiles ------------------
__global__ __launch_bounds__(256) void scanrow1_kernel(
    unsigned* __restrict__ hist1, unsigned* __restrict__ btotal1)
{
    const int t = threadIdx.x;
    const size_t base = (size_t)blockIdx.x * NT1MAX + t * 4;
    uint4 v = *(const uint4*)(hist1 + base);
    unsigned pre0 = 0, pre1 = v.x, pre2 = v.x + v.y, pre3 = v.x + v.y + v.z;
    unsigned run = pre3 + v.w;

    __shared__ unsigned ts[256];
    ts[t] = run;
    __syncthreads();
    for (int off = 1; off < 256; off <<= 1) {
        unsigned xv = (t >= off) ? ts[t - off] : 0u;
        __syncthreads();
        ts[t] += xv;
        __syncthreads();
    }
    unsigned ex = ts[t] - run;
    uint4 o = {ex + pre0, ex + pre1, ex + pre2, ex + pre3};
    *(uint4*)(hist1 + base) = o;
    if (t == 255) btotal1[blockIdx.x] = ts[255];
}

// ---- P1 base: coarse segment bases ------------------------------------------
__global__ void base1_kernel(const unsigned* __restrict__ btotal1,
                             unsigned* __restrict__ base1)
{
    if (threadIdx.x == 0) {
        unsigned r = 0;
        for (int k = 0; k < NK1; ++k) { base1[k] = r; r += btotal1[k]; }
        base1[NK1] = r;
    }
}

// ---- P1 scatter: LDS-staged, coalesced dump to coarse segments --------------
__global__ __launch_bounds__(256) void scatter1_kernel(
    const int* __restrict__ ci, const int* __restrict__ vi,
    const float* __restrict__ pol, const unsigned* __restrict__ hist1,
    const unsigned* __restrict__ base1, uint2* __restrict__ A, int n_edges)
{
    __shared__ unsigned sa[T1];            // 32 KB (cl)
    __shared__ unsigned sb[T1];            // 32 KB (v<<1|neg)
    __shared__ unsigned char bmap[T1];     //  8 KB
    __shared__ unsigned h[NK1], lst[NK1], h2[NK1], gst[NK1];

    const int t = threadIdx.x, b = blockIdx.x;
    if (t < NK1) h[t] = 0u;
    __syncthreads();
    const int e0 = b * T1, e1 = min(e0 + T1, n_edges), n = e1 - e0;
    for (int e = e0 + t; e < e1; e += 256)
        atomicAdd(&h[((unsigned)ci[e]) >> 15], 1u);
    __syncthreads();
    if (t == 0) {
        unsigned r = 0;
        for (int k = 0; k < NK1; ++k) { lst[k] = r; h2[k] = r; r += h[k]; }
    }
    __syncthreads();
    for (int e = e0 + t; e < e1; e += 256) {
        unsigned c = (unsigned)ci[e];
        unsigned v = (unsigned)vi[e];
        unsigned neg = (pol[e] < 0.f) ? 1u : 0u;
        unsigned k = c >> 15;
        unsigned p = atomicAdd(&h2[k], 1u);
        sa[p] = c; sb[p] = (v << 1) | neg; bmap[p] = (unsigned char)k;
    }
    if (t < NK1) gst[t] = base1[t] + hist1[(size_t)t * NT1MAX + b];
    __syncthreads();
    for (int s = t; s < n; s += 256) {
        unsigned k = bmap[s];
        A[gst[k] + (s - lst[k])] = make_uint2(sa[s], sb[s]);
    }
}

// ---- P2 hist: per (coarse, tile) histogram over 64 fine buckets -------------
__global__ __launch_bounds__(256) void hist2_kernel(
    const uint2* __restrict__ A, const unsigned* __restrict__ base1,
    unsigned* __restrict__ hist2)
{
    __shared__ unsigned h[64];
    const int t = threadIdx.x;
    const int k1 = blockIdx.x / MAXT2, i = blockIdx.x % MAXT2;
    const unsigned slo = base1[k1], shi = base1[k1 + 1];
    const unsigned t0 = slo + (unsigned)i * T2;
    if (t0 >= shi) return;
    const unsigned t1 = min(t0 + T2, shi);
    if (t < 64) h[t] = 0u;
    __syncthreads();
    for (unsigned e = t0 + t; e < t1; e += 256)
        atomicAdd(&h[(A[e].x >> CSHIFT) & 63], 1u);
    __syncthreads();
    if (t < 64) hist2[((size_t)(k1 * 64 + t)) * MAXT2 + i] = h[t];
}

// ---- P2 row scans: within-cbucket tile starts + cbucket totals --------------
__global__ __launch_bounds__(256) void scanrow2_kernel(
    unsigned* __restrict__ hist2, unsigned* __restrict__ ctotal)
{
    const int rid = blockIdx.x * 256 + threadIdx.x;   // 0..4095 == cbkt
    unsigned r = 0;
    for (int i = 0; i < MAXT2; ++i) {
        unsigned v = hist2[(size_t)rid * MAXT2 + i];
        hist2[(size_t)rid * MAXT2 + i] = r;
        r += v;
    }
    ctotal[rid] = r;
}

// ---- P2 base: global cbucket bases (bbase) ----------------------------------
__global__ __launch_bounds__(256) void bbase_kernel(
    const unsigned* __restrict__ ctotal, unsigned* __restrict__ bbase, int nb)
{
    const int t = threadIdx.x;
    unsigned loc[16];
    unsigned run = 0;
    #pragma unroll
    for (int it = 0; it < 16; ++it) {
        int idx = t * 16 + it;
        unsigned v = (idx < 4096) ? ctotal[idx] : 0u;
        loc[it] = run;
        run += v;
    }
    __shared__ unsigned ts[256];
    ts[t] = run;
    __syncthreads();
    for (int off = 1; off < 256; off <<= 1) {
        unsigned xv = (t >= off) ? ts[t - off] : 0u;
        __syncthreads();
        ts[t] += xv;
        __syncthreads();
    }
    unsigned ex = ts[t] - run;
    #pragma unroll
    for (int it = 0; it < 16; ++it) {
        int idx = t * 16 + it;
        if (idx <= nb) bbase[idx] = ex + loc[it];
    }
}

// ---- P2 scatter: LDS-staged, coalesced dump to final cbucket order ----------
__global__ __launch_bounds__(256) void scatter2_kernel(
    const uint2* __restrict__ A, const unsigned* __restrict__ base1,
    const unsigned* __restrict__ hist2, const unsigned* __restrict__ bbase,
    unsigned* __restrict__ sorted)
{
    __shared__ unsigned st[T2];            // 32 KB compact payloads
    __shared__ unsigned char bmap[T2];     //  8 KB
    __shared__ unsigned h[64], lst[64], h2[64], gst[64];

    const int t = threadIdx.x;
    const int k1 = blockIdx.x / MAXT2, i = blockIdx.x % MAXT2;
    const unsigned slo = base1[k1], shi = base1[k1 + 1];
    const unsigned t0 = slo + (unsigned)i * T2;
    if (t0 >= shi) return;
    const unsigned t1 = min(t0 + T2, shi);
    const int n = (int)(t1 - t0);
    if (t < 64) h[t] = 0u;
    __syncthreads();
    for (unsigned e = t0 + t; e < t1; e += 256)
        atomicAdd(&h[(A[e].x >> CSHIFT) & 63], 1u);
    __syncthreads();
    if (t == 0) {
        unsigned r = 0;
        for (int k = 0; k < 64; ++k) { lst[k] = r; h2[k] = r; r += h[k]; }
    }
    __syncthreads();
    for (unsigned e = t0 + t; e < t1; e += 256) {
        uint2 a = A[e];
        unsigned k2 = (a.x >> CSHIFT) & 63;
        unsigned p = atomicAdd(&h2[k2], 1u);
        st[p] = (a.x & (CB - 1)) | ((a.y >> 1) << CSHIFT) | ((a.y & 1u) << 28);
        bmap[p] = (unsigned char)k2;
    }
    if (t < 64) {
        unsigned cbk = (unsigned)(k1 * 64 + t);
        gst[t] = bbase[cbk] + hist2[(size_t)cbk * MAXT2 + i];
    }
    __syncthreads();
    for (int s = t; s < n; s += 256) {
        unsigned k = bmap[s];
        sorted[gst[k] + (s - lst[k])] = st[s];
    }
}

// ---------------- Pass 2: per-bucket clause-sort + register reduce -----------
__global__ __launch_bounds__(256) void bucket_kernel(
    const unsigned* __restrict__ sorted, const uint2* __restrict__ logit8,
    const unsigned* __restrict__ bbase, const int* __restrict__ clause_batch,
    float* __restrict__ per_graph, unsigned* __restrict__ gmask,
    int n_clauses, int n_graphs)
{
    __shared__ unsigned sarr[SARR_CAP];
    __shared__ unsigned cnt[CB];
    __shared__ unsigned cofs[CB];
    __shared__ unsigned cst[CB + 1];
    __shared__ unsigned gslot[CB];
    __shared__ unsigned cmsk[CB];
    __shared__ float pcl[K][CB];
    __shared__ float sp2[2][256];
    __shared__ unsigned ts[256];
    __shared__ int sh_ghi;

    const int t = threadIdx.x;
    const int bkt = blockIdx.x;
    const int c_base = bkt << CSHIFT;
    const int n_cl = min(CB, n_clauses - c_base);
    const int g_lo = clause_batch[c_base];

    {
        float v = __builtin_amdgcn_cvt_f32_fp8((unsigned)t, 0);
        float l = __logf(1.f + __expf(-fabsf(v)));
        sp2[0][t] = fmaxf(v, 0.f) + l;
        sp2[1][t] = fmaxf(-v, 0.f) + l;
    }
    for (int i = t; i < CB; i += 256) {
        cnt[i] = 0u;
        gslot[i] = (i < n_cl) ? (unsigned)(clause_batch[c_base + i] - g_lo) : 0xFFFFFFFFu;
    }
    if (t == 0) sh_ghi = clause_batch[c_base + n_cl - 1];
    __syncthreads();

    const unsigned lo = bbase[bkt], hi = bbase[bkt + 1];
    const int ne = (int)(hi - lo);

    if (ne <= SARR_CAP) {
        for (unsigned e = lo + t; e < hi; e += 256)
            atomicAdd(&cnt[sorted[e] & (CB - 1)], 1u);
        __syncthreads();

        unsigned a0 = cnt[2 * t], a1 = cnt[2 * t + 1];
        unsigned run = a0 + a1;
        ts[t] = run;
        __syncthreads();
        for (int off = 1; off < 256; off <<= 1) {
            unsigned xv = (t >= off) ? ts[t - off] : 0u;
            __syncthreads();
            ts[t] += xv;
            __syncthreads();
        }
        unsigned ex = ts[t] - run;
        cst[2 * t] = ex; cst[2 * t + 1] = ex + a0;
        cofs[2 * t] = ex; cofs[2 * t + 1] = ex + a0;
        if (t == 255) cst[CB] = ex + run;
        __syncthreads();

        for (unsigned e = lo + t; e < hi; e += 256) {
            unsigned pay = sorted[e];
            unsigned r = atomicAdd(&cofs[pay & (CB - 1)], 1u);
            sarr[r] = pay;
        }
        __syncthreads();

        #pragma unroll
        for (int oc = 0; oc < 2; ++oc) {
            int cl = 2 * t + oc;
            if (cl >= n_cl) continue;
            unsigned s0 = cst[cl];
            int n = (int)(cst[cl + 1] - s0);
            float sums[K] = {0.f, 0.f, 0.f, 0.f, 0.f, 0.f, 0.f, 0.f};
            unsigned ormask = 0u;
            for (int base = 0; base < n; base += 8) {
                int m = min(8, n - base);
                unsigned pays[8]; uint2 gs[8];
                for (int i = 0; i < m; ++i) pays[i] = sarr[s0 + base + i];
                for (int i = 0; i < m; ++i) gs[i] = logit8[(pays[i] >> CSHIFT) & 0x7FFFF];
                for (int i = 0; i < m; ++i) {
                    unsigned neg = (pays[i] >> 28) & 1u;
                    const float* spt = sp2[neg];
                    unsigned gt0 = 0u;
                    #pragma unroll
                    for (int j = 0; j < 4; ++j) {
                        unsigned b0 = (gs[i].x >> (8 * j)) & 0xFFu;
                        unsigned b1 = (gs[i].y >> (8 * j)) & 0xFFu;
                        sums[j]     += spt[b0];
                        sums[j + 4] += spt[b1];
                        gt0 |= (b0 - 1u < 0x7Fu) ? (1u << j) : 0u;
                        gt0 |= (b1 - 1u < 0x7Fu) ? (1u << (j + 4)) : 0u;
                    }
                    ormask |= gt0 ^ (neg ? 0xFFu : 0u);
                }
            }
            #pragma unroll
            for (int j = 0; j < K; ++j) {
                float cv = __expf(-sums[j]);
                pcl[j][cl] = cv * (-__logf(1.f - cv + EPS));
            }
            cmsk[cl] = ormask;
        }
    } else {
        for (int i = t; i < K * CB; i += 256) ((float*)pcl)[i] = 0.f;
        for (int i = t; i < CB; i += 256) cmsk[i] = 0u;
        __syncthreads();
        for (unsigned e = lo + t; e < hi; e += 256) {
            unsigned pay = sorted[e];
            uint2 g = logit8[(pay >> CSHIFT) & 0x7FFFF];
            unsigned cl = pay & (CB - 1);
            unsigned neg = (pay >> 28) & 1u;
            const float* spt = sp2[neg];
            unsigned gt0 = 0u;
            #pragma unroll
            for (int j = 0; j < 4; ++j) {
                unsigned b0 = (g.x >> (8 * j)) & 0xFFu;
                unsigned b1 = (g.y >> (8 * j)) & 0xFFu;
                atomicAdd(&pcl[j][cl], spt[b0]);
                atomicAdd(&pcl[j + 4][cl], spt[b1]);
                gt0 |= (b0 - 1u < 0x7Fu) ? (1u << j) : 0u;
                gt0 |= (b1 - 1u < 0x7Fu) ? (1u << (j + 4)) : 0u;
            }
            atomicOr(&cmsk[cl], (gt0 ^ (neg ? 0xFFu : 0u)) | 0x100u);
        }
        __syncthreads();
        for (int oc = 0; oc < 2; ++oc) {
            int cl = 2 * t + oc;
            if (cl >= n_cl) continue;
            #pragma unroll
            for (int j = 0; j < K; ++j) {
                float cv = __expf(-pcl[j][cl]);
                pcl[j][cl] = cv * (-__logf(1.f - cv + EPS));
            }
            unsigned cm = cmsk[cl];
            cmsk[cl] = (cm & 0x100u) ? (cm & 0xFFu) : 0u;
        }
    }
    __syncthreads();

    const int nslots = sh_ghi - g_lo + 1;
    for (int s = (t >> 3); s < nslots; s += 32) {
        int j = t & 7;
        float a = 0.f;
        for (int cl = 0; cl < n_cl; ++cl)
            if (gslot[cl] == (unsigned)s) a += pcl[j][cl];
        atomicAdd(&per_graph[(size_t)(g_lo + s) * K + j], a);
    }
    for (int s = t; s < nslots; s += 256) {
        unsigned m = 0xFFu;
        for (int cl = 0; cl < n_cl; ++cl)
            if (gslot[cl] == (unsigned)s) m &= cmsk[cl];
        atomicAnd(&gmask[g_lo + s], m);
    }
}

// ---------------- Final: per-graph sqrt, sort-8, cost dot, solved ------------
__global__ __launch_bounds__(256) void final_kernel(
    const float* __restrict__ per_graph, const unsigned* __restrict__ gmask,
    int n_graphs, float* __restrict__ out)
{
    const int t = threadIdx.x;
    float dot = 0.f;
    if (t < n_graphs) {
        float v[K];
        #pragma unroll
        for (int j = 0; j < K; ++j)
            v[j] = sqrtf(per_graph[(size_t)t * K + j] + SQRT_EPS) - sqrtf(SQRT_EPS);
        #pragma unroll
        for (int i = 1; i < K; ++i) {
            float key = v[i];
            int j = i - 1;
            while (j >= 0 && v[j] < key) { v[j + 1] = v[j]; --j; }
            v[j + 1] = key;
        }
        #pragma unroll
        for (int i = 0; i < K; ++i)
            dot = fmaf(v[i], (float)((i + 1) * (i + 1)), dot);
        out[1 + t] = (gmask[t] & 0xFFu) ? 1.f : 0.f;
    }
    __shared__ float red[256];
    red[t] = dot;
    __syncthreads();
    for (int s = 128; s >= 1; s >>= 1) {
        if (t < s) red[t] += red[t + s];
        __syncthreads();
    }
    if (t == 0) out[0] = red[0] * (1.f / 204.f);
}

// ---------------------------------------------------------------------------
extern "C" void kernel_launch(void* const* d_in, const int* in_sizes, int n_in,
                              void* d_out, int out_size, void* d_ws, size_t ws_size,
                              hipStream_t stream) {
    const float* x   = (const float*)d_in[0];
    const float* pol = (const float*)d_in[1];
    const int* vi    = (const int*)d_in[2];
    const int* ci    = (const int*)d_in[3];
    const int* cb    = (const int*)d_in[4];
    const float* W1  = (const float*)d_in[5];
    const float* b1  = (const float*)d_in[6];
    const float* W2  = (const float*)d_in[7];
    const float* b2  = (const float*)d_in[8];

    const int n_vars    = in_sizes[0] / DIM;
    const int n_edges   = in_sizes[1];
    const int n_clauses = in_sizes[4];
    const int n_graphs  = out_size - 1;
    const int nb        = (n_clauses + CB - 1) / CB;
    const int nt1       = (n_edges + T1 - 1) / T1;

    // ---- workspace layout (256B aligned regions) ----
    char* ws = (char*)d_ws;
    size_t off = 0;
    auto alloc = [&](size_t bytes) { char* p = ws + off; off += (bytes + 255) & ~(size_t)255; return p; };
    uint2*    lfp8     = (uint2*)alloc((size_t)n_vars * 8);                // 4 MB fp8
    unsigned* sorted   = (unsigned*)alloc((size_t)n_edges * 4);            // 24 MB
    uint2*    A        = (uint2*)alloc((size_t)n_edges * 8);               // 48 MB
    unsigned* hist1    = (unsigned*)alloc((size_t)NK1 * NT1MAX * 4);       // 256 KB
    unsigned* btotal1  = (unsigned*)alloc((size_t)(NK1 + 1) * 4);
    unsigned* base1    = (unsigned*)alloc((size_t)(NK1 + 1) * 4);
    unsigned* hist2    = (unsigned*)alloc((size_t)4096 * MAXT2 * 4);       // 768 KB
    unsigned* ctotal   = (unsigned*)alloc((size_t)4096 * 4);
    unsigned* bbase    = (unsigned*)alloc((size_t)(NBMAX + 1) * 4);
    float*    per_graph= (float*)alloc((size_t)n_graphs * K * 4);
    unsigned* gmask    = (unsigned*)alloc((size_t)n_graphs * 4);

    hipMemsetAsync(hist1, 0, (size_t)NK1 * NT1MAX * 4, stream);
    hipMemsetAsync(hist2, 0, (size_t)4096 * MAXT2 * 4, stream);
    hipMemsetAsync(per_graph, 0, (size_t)n_graphs * K * 4, stream);
    hipMemsetAsync(gmask, 0xFF, (size_t)n_graphs * 4, stream);

    hist1_kernel<<<nt1, 256, 0, stream>>>(ci, hist1, n_edges);
    scanrow1_kernel<<<NK1, 256, 0, stream>>>(hist1, btotal1);
    base1_kernel<<<1, 64, 0, stream>>>(btotal1, base1);
    scatter1_kernel<<<nt1, 256, 0, stream>>>(ci, vi, pol, hist1, base1, A, n_edges);
    hist2_kernel<<<NK1 * MAXT2, 256, 0, stream>>>(A, base1, hist2);
    scanrow2_kernel<<<16, 256, 0, stream>>>(hist2, ctotal);
    bbase_kernel<<<1, 256, 0, stream>>>(ctotal, bbase, nb);
    scatter2_kernel<<<NK1 * MAXT2, 256, 0, stream>>>(A, base1, hist2, bbase, sorted);
    mlp_kernel<<<(n_vars + 127) / 128, 256, 0, stream>>>(x, W1, b1, W2, b2, lfp8, n_vars);
    bucket_kernel<<<nb, 256, 0, stream>>>(sorted, lfp8, bbase, cb,
                                          per_graph, gmask, n_clauses, n_graphs);
    final_kernel<<<1, 256, 0, stream>>>(per_graph, gmask, n_graphs, (float*)d_out);
}